// Round 19
// baseline (631.161 us; speedup 1.0000x reference)
//
#include <hip/hip_runtime.h>
#include <hip/hip_bf16.h>

#define T_TOK 8192
#define DIM   1024
#define HID   4096
#define NE    8
#define RCAP  (T_TOK * 2 + 256)

typedef unsigned short u16;
typedef unsigned int   u32;
typedef float  f32x4 __attribute__((ext_vector_type(4)));
typedef __bf16 bf16x8 __attribute__((ext_vector_type(8)));

__device__ __forceinline__ u16 f2bf(float f) {
    u32 u = __builtin_bit_cast(u32, f);
    return (u16)((u + 0x7FFFu + ((u >> 16) & 1u)) >> 16);
}
__device__ __forceinline__ u32 pk2(float a, float b) {
    return (u32)f2bf(a) | ((u32)f2bf(b) << 16);
}
__device__ __forceinline__ float bf2f(u16 u) {
    return __builtin_bit_cast(float, (u32)u << 16);
}

#define GLOAD_LDS16(g, l) \
    __builtin_amdgcn_global_load_lds((const __attribute__((address_space(1))) u32*)(g), \
                                     (__attribute__((address_space(3))) u32*)(l), 16, 0, 0)

// ---------------- router: one wave per token; counters padded (1/line) ----------------
__global__ __launch_bounds__(256) void router_kernel(
    const float* __restrict__ x, const float* __restrict__ gw,
    int* __restrict__ tok_e, float* __restrict__ tok_w, int* __restrict__ cnt)
{
    int wid  = threadIdx.x >> 6;
    int lane = threadIdx.x & 63;
    int t = blockIdx.x * 4 + wid;

    const float4* xp = (const float4*)(x + (size_t)t * DIM);
    float4 xv[4];
    #pragma unroll
    for (int c = 0; c < 4; ++c) xv[c] = xp[c * 64 + lane];

    float r[NE];
    #pragma unroll
    for (int e = 0; e < NE; ++e) {
        const float4* gp = (const float4*)(gw + e * DIM);
        float acc = 0.f;
        #pragma unroll
        for (int c = 0; c < 4; ++c) {
            float4 g = gp[c * 64 + lane];
            acc += xv[c].x * g.x + xv[c].y * g.y + xv[c].z * g.z + xv[c].w * g.w;
        }
        r[e] = acc;
    }
    #pragma unroll
    for (int s = 1; s < 64; s <<= 1) {
        #pragma unroll
        for (int e = 0; e < NE; ++e) r[e] += __shfl_xor(r[e], s);
    }
    if (lane == 0) {
        int e0 = 0; float l0 = r[0];
        #pragma unroll
        for (int e = 1; e < NE; ++e) if (r[e] > l0) { l0 = r[e]; e0 = e; }
        int e1 = -1; float l1 = -3e38f;
        #pragma unroll
        for (int e = 0; e < NE; ++e) if (e != e0 && r[e] > l1) { l1 = r[e]; e1 = e; }
        float d  = __expf(l1 - l0);          // <= 1
        float w0 = 1.f / (1.f + d);
        float w1 = d * w0;
        tok_e[t * 2]     = e0;  tok_e[t * 2 + 1] = e1;
        tok_w[t * 2]     = w0;  tok_w[t * 2 + 1] = w1;
        atomicAdd(&cnt[e0 * 16], 1);
        atomicAdd(&cnt[e1 * 16], 1);
    }
}

// ---------------- prefix: bases + item cumsums ----------------
__global__ void prefix_kernel(const int* __restrict__ cnt, int* __restrict__ base,
                              int* __restrict__ qmeta)
{
    if (threadIdx.x == 0) {
        int* cum1 = qmeta;        // [9]
        int* cum2 = qmeta + 16;   // [9]
        int s = 0, c1 = 0, c2 = 0;
        cum1[0] = 0; cum2[0] = 0;
        for (int e = 0; e < NE; ++e) {
            base[e] = s; s += cnt[e * 16];
            int mts = (cnt[e * 16] + 255) >> 8;
            c1 += mts * (HID / 256);       cum1[e + 1] = c1;
            c2 += mts * 2 * (DIM / 256);   cum2[e + 1] = c2;
        }
        qmeta[32] = 0;   // qcur1
        qmeta[33] = 0;   // qcur2
    }
}

// ---------------- scatter: 32 tokens/block, LDS ranks, 8 padded atomics/block ----------------
__global__ __launch_bounds__(256) void scatter_kernel(
    const float* __restrict__ x, const int* __restrict__ tok_e,
    const int* __restrict__ base, int* __restrict__ cursor,
    int* __restrict__ invrow, u16* __restrict__ A1)
{
    __shared__ int hist[NE], gbase[NE], rows[64];
    int b  = blockIdx.x;
    int t0 = b * 32;
    if (threadIdx.x < NE) hist[threadIdx.x] = 0;
    __syncthreads();
    if (threadIdx.x == 0) {
        for (int s = 0; s < 64; ++s) {
            int e = tok_e[t0 * 2 + s];
            rows[s] = hist[e]++;
        }
        for (int e = 0; e < NE; ++e)
            gbase[e] = atomicAdd(&cursor[e * 16], hist[e]);
        for (int s = 0; s < 64; ++s) {
            int e = tok_e[t0 * 2 + s];
            int row = base[e] + gbase[e] + rows[s];
            rows[s] = row;
            invrow[t0 * 2 + s] = row;
        }
    }
    __syncthreads();
    int i = threadIdx.x;
    for (int t = 0; t < 32; ++t) {
        float4 xv = ((const float4*)(x + (size_t)(t0 + t) * DIM))[i];
        u32 p0 = pk2(xv.x, xv.y);
        u32 p1 = pk2(xv.z, xv.w);
        int r0 = rows[2 * t], r1 = rows[2 * t + 1];
        u32* d0 = (u32*)(A1 + (size_t)r0 * DIM) + i * 2;
        d0[0] = p0; d0[1] = p1;
        u32* d1 = (u32*)(A1 + (size_t)r1 * DIM) + i * 2;
        d1[0] = p0; d1[1] = p1;
    }
}

// ---------------- fp32 -> bf16 weight conversion ----------------
__global__ __launch_bounds__(256) void convw_kernel(
    const float* __restrict__ W1, const float* __restrict__ W2,
    u16* __restrict__ W1b, u16* __restrict__ W2b)
{
    const size_t n8 = (size_t)NE * HID * DIM / 8;
    size_t stride = (size_t)gridDim.x * blockDim.x;
    for (size_t i = blockIdx.x * (size_t)blockDim.x + threadIdx.x; i < 2 * n8; i += stride) {
        const float* src = (i < n8) ? W1 : W2;
        u16*         dst = (i < n8) ? W1b : W2b;
        size_t j = (i < n8) ? i : i - n8;
        float4 a = ((const float4*)src)[j * 2];
        float4 b = ((const float4*)src)[j * 2 + 1];
        uint4 o;
        o.x = pk2(a.x, a.y); o.y = pk2(a.z, a.w);
        o.z = pk2(b.x, b.y); o.w = pk2(b.z, b.w);
        ((uint4*)dst)[j] = o;
    }
}

// ---------------- persistent grouped GEMM — BK=64, 2-slot ring, 1 barrier/tile ----------------
// 256x256 tile, BK=64, 8 waves (2Mx4N). 2 LDS slots x 64 KB. Per K-tile:
// barrier -> STAGE(kt+1) -> issue g1(8)+g2(4)+g3(8) ds_reads (pinned) ->
// lgkm cascade (all counts <= 15, 4-bit field): wait(12) [g1 done] -> cluster1
// -> issue g4(4) -> wait(12) [g2 done; g3+g4=12 remain] -> cluster2 ->
// wait(4) [g3 done] -> cluster3 -> wait(0) -> cluster4 -> vmcnt(0) (kt+1's
// loads, issued a full tile body earlier). Slot (kt+1)&1 free at barrier(kt).
// 128-B-row swizzle: LDS(r,g) holds global group g^(r&7); staging source
// col-group (tid&7)^((tid>>3)&7); read group ((lane>>4)+4ks)^(lane&7).
template<int KDIM, int NDIM, bool IS_G2>
__global__ __launch_bounds__(512, 1) void moe_gemm(
    const u16* __restrict__ A, const u16* __restrict__ B,
    const float* __restrict__ bias,
    u16* __restrict__ Hout, u16* __restrict__ Y0, u16* __restrict__ Y1,
    const int* __restrict__ cnt, const int* __restrict__ base,
    const int* __restrict__ cum, int* __restrict__ qcur)
{
    constexpr int KLEN = IS_G2 ? (KDIM / 2) : KDIM;   // split-K=2 for GEMM2
    constexpr int NKT  = KLEN / 64;                   // 16 (G1) / 32 (G2)

    __shared__ u16 lds[2 * 32768];        // 2 slots x (A 256x64 + B 256x64)
    __shared__ int sitem;

    int tid  = threadIdx.x;
    int lane = tid & 63;
    int w    = tid >> 6;
    int wr   = w >> 2, wc = w & 3;

    // fragment-read offsets (u16), 128-B rows: row*64 + swizzled 16B-group*8
    int l7 = lane & 7;
    int aOff0 = (wr * 128 + (lane & 15)) * 64 + ((((lane >> 4) + 0) ^ l7) * 8);
    int aOff1 = (wr * 128 + (lane & 15)) * 64 + ((((lane >> 4) + 4) ^ l7) * 8);
    int bOff0 = 16384 + (wc * 64 + (lane & 15)) * 64 + ((((lane >> 4) + 0) ^ l7) * 8);
    int bOff1 = 16384 + (wc * 64 + (lane & 15)) * 64 + ((((lane >> 4) + 4) ^ l7) * 8);

    // staging: LDS dest linear (row = rd*64 + tid>>3, group = tid&7);
    // global source col-group inverse-permuted by row&7
    int scol = (((tid & 7) ^ ((tid >> 3) & 7)) * 8);
    u16* dA = lds + tid * 8;
    u16* dB = lds + 16384 + tid * 8;

    int total = cum[NE];

    for (;;) {
        __syncthreads();                  // protects sitem & LDS reuse across items
        if (tid == 0) {
            int p = atomicAdd(qcur, 1);
            int it = -1;
            if (p < total) {
                int e = 0;
                while (p >= cum[e + 1]) ++e;
                int r   = p - cum[e];
                int mts = (cnt[e * 16] + 255) >> 8;
                int ks = 0, nt, mt;
                if (IS_G2) { int ksnt = r / mts; mt = r - ksnt * mts; ks = ksnt >> 2; nt = ksnt & 3; }
                else       { nt = r / mts; mt = r - nt * mts; }
                it = (e << 16) | (ks << 12) | (nt << 8) | mt;
            }
            sitem = it;
        }
        __syncthreads();
        int item = sitem;
        if (item < 0) break;

        int e  = item >> 16;
        int ks = (item >> 12) & 15;
        int nt = (item >> 8) & 15;
        int mt = item & 255;
        int ce = cnt[e * 16];
        int m0 = base[e] + mt * 256;
        int n0 = nt * 256;
        int k0 = ks * KLEN;

        const u16* aSr = A + (size_t)(m0 + (tid >> 3)) * KDIM + k0 + scol;
        const u16* bSr = B + (size_t)e * NDIM * KDIM + (size_t)(n0 + (tid >> 3)) * KDIM + k0 + scol;

#define STAGE(kt_) do { int s_ = ((kt_) & 1) * 32768; size_t ko_ = (size_t)(kt_) * 64;   \
        _Pragma("unroll")                                                                \
        for (int rd_ = 0; rd_ < 4; ++rd_) {                                              \
            GLOAD_LDS16(aSr + ko_ + (size_t)(rd_ * 64) * KDIM, dA + s_ + rd_ * 4096);    \
            GLOAD_LDS16(bSr + ko_ + (size_t)(rd_ * 64) * KDIM, dB + s_ + rd_ * 4096);    \
        }                                                                                \
    } while (0)

        f32x4 acc[8][4];
        #pragma unroll
        for (int m = 0; m < 8; ++m)
            #pragma unroll
            for (int n = 0; n < 4; ++n)
                #pragma unroll
                for (int i = 0; i < 4; ++i) acc[m][n][i] = 0.f;

        // prologue: tile 0 staged and landed
        STAGE(0);
        asm volatile("s_waitcnt vmcnt(0)" ::: "memory");

        for (int kt = 0; kt < NKT; ++kt) {
            __builtin_amdgcn_s_barrier();          // tile kt published; slot (kt+1)&1 free
            __builtin_amdgcn_sched_barrier(0);
            if (kt + 1 < NKT) STAGE(kt + 1);
            __builtin_amdgcn_sched_barrier(0);

            int bo = (kt & 1) * 32768;
            bf16x8 a0[8], b0v[4], a1[8], b1v[4];
            // group 1: a0[0-3] + b0v (8 reads) — cluster 1
            #pragma unroll
            for (int m = 0; m < 4; ++m) a0[m] = *(const bf16x8*)(lds + bo + aOff0 + m * 1024);
            #pragma unroll
            for (int n = 0; n < 4; ++n) b0v[n] = *(const bf16x8*)(lds + bo + bOff0 + n * 1024);
            __builtin_amdgcn_sched_barrier(0);
            // group 2: a0[4-7] (4 reads) — cluster 2
            #pragma unroll
            for (int m = 4; m < 8; ++m) a0[m] = *(const bf16x8*)(lds + bo + aOff0 + m * 1024);
            __builtin_amdgcn_sched_barrier(0);
            // group 3: a1[0-3] + b1v (8 reads) — cluster 3
            #pragma unroll
            for (int m = 0; m < 4; ++m) a1[m] = *(const bf16x8*)(lds + bo + aOff1 + m * 1024);
            #pragma unroll
            for (int n = 0; n < 4; ++n) b1v[n] = *(const bf16x8*)(lds + bo + bOff1 + n * 1024);
            __builtin_amdgcn_sched_barrier(0);

            asm volatile("s_waitcnt lgkmcnt(12)" ::: "memory");   // g1 done (g2+g3 remain)
            __builtin_amdgcn_sched_barrier(0);
            __builtin_amdgcn_s_setprio(1);
            #pragma unroll
            for (int m = 0; m < 4; ++m)
                #pragma unroll
                for (int n = 0; n < 4; ++n)
                    acc[m][n] = __builtin_amdgcn_mfma_f32_16x16x32_bf16(a0[m], b0v[n], acc[m][n], 0, 0, 0);
            __builtin_amdgcn_s_setprio(0);
            __builtin_amdgcn_sched_barrier(0);

            // group 4: a1[4-7] (4 reads) — cluster 4 (issued late: keeps counts <= 15)
            #pragma unroll
            for (int m = 4; m < 8; ++m) a1[m] = *(const bf16x8*)(lds + bo + aOff1 + m * 1024);
            __builtin_amdgcn_sched_barrier(0);

            asm volatile("s_waitcnt lgkmcnt(12)" ::: "memory");   // g2 done (g3+g4=12 remain)
            __builtin_amdgcn_sched_barrier(0);
            __builtin_amdgcn_s_setprio(1);
            #pragma unroll
            for (int m = 4; m < 8; ++m)
                #pragma unroll
                for (int n = 0; n < 4; ++n)
                    acc[m][n] = __builtin_amdgcn_mfma_f32_16x16x32_bf16(a0[m], b0v[n], acc[m][n], 0, 0, 0);
            __builtin_amdgcn_s_setprio(0);

            asm volatile("s_waitcnt lgkmcnt(4)" ::: "memory");    // g3 done
            __builtin_amdgcn_sched_barrier(0);
            __builtin_amdgcn_s_setprio(1);
            #pragma unroll
            for (int m = 0; m < 4; ++m)
                #pragma unroll
                for (int n = 0; n < 4; ++n)
                    acc[m][n] = __builtin_amdgcn_mfma_f32_16x16x32_bf16(a1[m], b1v[n], acc[m][n], 0, 0, 0);
            __builtin_amdgcn_s_setprio(0);

            asm volatile("s_waitcnt lgkmcnt(0)" ::: "memory");    // g4 done
            __builtin_amdgcn_sched_barrier(0);
            __builtin_amdgcn_s_setprio(1);
            #pragma unroll
            for (int m = 4; m < 8; ++m)
                #pragma unroll
                for (int n = 0; n < 4; ++n)
                    acc[m][n] = __builtin_amdgcn_mfma_f32_16x16x32_bf16(a1[m], b1v[n], acc[m][n], 0, 0, 0);
            __builtin_amdgcn_s_setprio(0);
            __builtin_amdgcn_sched_barrier(0);

            // kt+1's stage loads landed (issued a full tile body ago)
            if (kt + 1 < NKT) asm volatile("s_waitcnt vmcnt(0)" ::: "memory");
        }
#undef STAGE

        // epilogue: C/D layout col = lane&15, row = (lane>>4)*4 + reg
        #pragma unroll
        for (int m = 0; m < 8; ++m) {
            #pragma unroll
            for (int j = 0; j < 4; ++j) {
                int rr   = wr * 128 + m * 16 + (lane >> 4) * 4 + j;
                int rloc = mt * 256 + rr;
                if (rloc < ce) {
                    if (!IS_G2) {
                        u16* hp = Hout + (size_t)(m0 + rr) * NDIM;
                        #pragma unroll
                        for (int n = 0; n < 4; ++n) {
                            int gcol = n0 + wc * 64 + n * 16 + (lane & 15);
                            float v = acc[m][n][j] + bias[e * NDIM + gcol];
                            v = v > 0.f ? v : 0.f;
                            hp[gcol] = f2bf(v);
                        }
                    } else {
                        u16* yp = (ks == 0 ? Y0 : Y1) + (size_t)(m0 + rr) * NDIM;
                        #pragma unroll
                        for (int n = 0; n < 4; ++n) {
                            int gcol = n0 + wc * 64 + n * 16 + (lane & 15);
                            float v = acc[m][n][j];
                            if (ks == 0) v += bias[e * NDIM + gcol];
                            yp[gcol] = f2bf(v);
                        }
                    }
                }
            }
        }
        asm volatile("s_waitcnt vmcnt(0)" ::: "memory");   // drain stores before next item
    }
}

// ---------------- combine (bf16 partials): out = w0*(Y0[r0]+Y1[r0]) + w1*(Y0[r1]+Y1[r1]) ----------------
__global__ __launch_bounds__(256) void combine_kernel(
    const u16* __restrict__ Y0, const u16* __restrict__ Y1,
    const int* __restrict__ invrow, const float* __restrict__ tok_w,
    float* __restrict__ out)
{
    int t  = blockIdx.x;
    int r0 = invrow[t * 2], r1 = invrow[t * 2 + 1];
    float w0 = tok_w[t * 2], w1 = tok_w[t * 2 + 1];
    int i = threadIdx.x;
    ushort4 a0 = ((const ushort4*)(Y0 + (size_t)r0 * DIM))[i];
    ushort4 b0 = ((const ushort4*)(Y1 + (size_t)r0 * DIM))[i];
    ushort4 a1 = ((const ushort4*)(Y0 + (size_t)r1 * DIM))[i];
    ushort4 b1 = ((const ushort4*)(Y1 + (size_t)r1 * DIM))[i];
    float4 o;
    o.x = w0 * (bf2f(a0.x) + bf2f(b0.x)) + w1 * (bf2f(a1.x) + bf2f(b1.x));
    o.y = w0 * (bf2f(a0.y) + bf2f(b0.y)) + w1 * (bf2f(a1.y) + bf2f(b1.y));
    o.z = w0 * (bf2f(a0.z) + bf2f(b0.z)) + w1 * (bf2f(a1.z) + bf2f(b1.z));
    o.w = w0 * (bf2f(a0.w) + bf2f(b0.w)) + w1 * (bf2f(a1.w) + bf2f(b1.w));
    ((float4*)(out + (size_t)t * DIM))[i] = o;
}

extern "C" void kernel_launch(void* const* d_in, const int* in_sizes, int n_in,
                              void* d_out, int out_size, void* d_ws, size_t ws_size,
                              hipStream_t stream) {
    const float* xs = (const float*)d_in[0];
    const float* gw = (const float*)d_in[1];
    const float* W1 = (const float*)d_in[2];
    const float* b1 = (const float*)d_in[3];
    const float* W2 = (const float*)d_in[4];
    const float* b2 = (const float*)d_in[5];
    float* out = (float*)d_out;

    char* ws = (char*)d_ws;
    size_t off = 0;
    auto alloc = [&](size_t bytes) -> void* {
        off = (off + 255) & ~(size_t)255;
        void* p = ws + off;
        off += bytes;
        return p;
    };
    int*   ctrs   = (int*)alloc(2048);          // cnt[e*16] @0, cursor[e*16] @+128 ints
    int*   cnt    = ctrs;
    int*   cursor = ctrs + 128;
    int*   base   = (int*)alloc(64);
    int*   qmeta  = (int*)alloc(256);           // cum1[9], cum2[9]@16, qcur@32,33
    int*   tok_e  = (int*)alloc((size_t)T_TOK * 2 * 4);
    float* tok_w  = (float*)alloc((size_t)T_TOK * 2 * 4);
    int*   invrow = (int*)alloc((size_t)T_TOK * 2 * 4);
    u16*   A1     = (u16*)alloc((size_t)RCAP * DIM * 2);       // 34 MB
    u16*   W1b    = (u16*)alloc((size_t)NE * HID * DIM * 2);   // 64 MB
    u16*   W2b    = (u16*)alloc((size_t)NE * HID * DIM * 2);   // 64 MB
    u16*   hbuf   = (u16*)alloc((size_t)RCAP * HID * 2);       // 136 MB
    u16*   Ypart0 = (u16*)alloc((size_t)RCAP * DIM * 2);       // 34 MB bf16
    u16*   Ypart1 = (u16*)alloc((size_t)RCAP * DIM * 2);       // 34 MB bf16
    (void)ws_size; (void)in_sizes; (void)n_in; (void)out_size;

    hipMemsetAsync(ctrs, 0, 2048, stream);

    router_kernel<<<T_TOK / 4, 256, 0, stream>>>(xs, gw, tok_e, tok_w, cnt);
    prefix_kernel<<<1, 64, 0, stream>>>(cnt, base, qmeta);
    scatter_kernel<<<T_TOK / 32, 256, 0, stream>>>(xs, tok_e, base, cursor, invrow, A1);
    convw_kernel<<<2048, 256, 0, stream>>>(W1, W2, W1b, W2b);

    moe_gemm<DIM, HID, false><<<256, 512, 0, stream>>>(
        A1, W1b, b1, hbuf, nullptr, nullptr, cnt, base, qmeta, qmeta + 32);
    moe_gemm<HID, DIM, true><<<256, 512, 0, stream>>>(
        hbuf, W2b, b2, nullptr, Ypart0, Ypart1, cnt, base, qmeta + 16, qmeta + 33);

    combine_kernel<<<T_TOK, 256, 0, stream>>>(Ypart0, Ypart1, invrow, tok_w, out);
}

// Round 20
// 554.907 us; speedup vs baseline: 1.1374x; 1.1374x over previous
//
#include <hip/hip_runtime.h>
#include <hip/hip_bf16.h>

#define T_TOK 8192
#define DIM   1024
#define HID   4096
#define NE    8
#define RCAP  (T_TOK * 2 + 256)

typedef unsigned short u16;
typedef unsigned int   u32;
typedef float  f32x4 __attribute__((ext_vector_type(4)));
typedef __bf16 bf16x8 __attribute__((ext_vector_type(8)));

__device__ __forceinline__ u16 f2bf(float f) {
    u32 u = __builtin_bit_cast(u32, f);
    return (u16)((u + 0x7FFFu + ((u >> 16) & 1u)) >> 16);
}
__device__ __forceinline__ u32 pk2(float a, float b) {
    return (u32)f2bf(a) | ((u32)f2bf(b) << 16);
}
__device__ __forceinline__ float bf2f(u16 u) {
    return __builtin_bit_cast(float, (u32)u << 16);
}

#define GLOAD_LDS16(g, l) \
    __builtin_amdgcn_global_load_lds((const __attribute__((address_space(1))) u32*)(g), \
                                     (__attribute__((address_space(3))) u32*)(l), 16, 0, 0)

// ---------------- router: one wave per token; counters padded (1/line) ----------------
__global__ __launch_bounds__(256) void router_kernel(
    const float* __restrict__ x, const float* __restrict__ gw,
    int* __restrict__ tok_e, float* __restrict__ tok_w, int* __restrict__ cnt)
{
    int wid  = threadIdx.x >> 6;
    int lane = threadIdx.x & 63;
    int t = blockIdx.x * 4 + wid;

    const float4* xp = (const float4*)(x + (size_t)t * DIM);
    float4 xv[4];
    #pragma unroll
    for (int c = 0; c < 4; ++c) xv[c] = xp[c * 64 + lane];

    float r[NE];
    #pragma unroll
    for (int e = 0; e < NE; ++e) {
        const float4* gp = (const float4*)(gw + e * DIM);
        float acc = 0.f;
        #pragma unroll
        for (int c = 0; c < 4; ++c) {
            float4 g = gp[c * 64 + lane];
            acc += xv[c].x * g.x + xv[c].y * g.y + xv[c].z * g.z + xv[c].w * g.w;
        }
        r[e] = acc;
    }
    #pragma unroll
    for (int s = 1; s < 64; s <<= 1) {
        #pragma unroll
        for (int e = 0; e < NE; ++e) r[e] += __shfl_xor(r[e], s);
    }
    if (lane == 0) {
        int e0 = 0; float l0 = r[0];
        #pragma unroll
        for (int e = 1; e < NE; ++e) if (r[e] > l0) { l0 = r[e]; e0 = e; }
        int e1 = -1; float l1 = -3e38f;
        #pragma unroll
        for (int e = 0; e < NE; ++e) if (e != e0 && r[e] > l1) { l1 = r[e]; e1 = e; }
        float d  = __expf(l1 - l0);          // <= 1
        float w0 = 1.f / (1.f + d);
        float w1 = d * w0;
        tok_e[t * 2]     = e0;  tok_e[t * 2 + 1] = e1;
        tok_w[t * 2]     = w0;  tok_w[t * 2 + 1] = w1;
        atomicAdd(&cnt[e0 * 16], 1);
        atomicAdd(&cnt[e1 * 16], 1);
    }
}

// ---------------- prefix: bases + item cumsums ----------------
__global__ void prefix_kernel(const int* __restrict__ cnt, int* __restrict__ base,
                              int* __restrict__ qmeta)
{
    if (threadIdx.x == 0) {
        int* cum1 = qmeta;        // [9]
        int* cum2 = qmeta + 16;   // [9]
        int s = 0, c1 = 0, c2 = 0;
        cum1[0] = 0; cum2[0] = 0;
        for (int e = 0; e < NE; ++e) {
            base[e] = s; s += cnt[e * 16];
            int mts = (cnt[e * 16] + 255) >> 8;
            c1 += mts * (HID / 256);       cum1[e + 1] = c1;
            c2 += mts * 2 * (DIM / 256);   cum2[e + 1] = c2;
        }
        qmeta[32] = 0;   // qcur1
        qmeta[33] = 0;   // qcur2
    }
}

// ---------------- scatter: 32 tokens/block, LDS ranks, 8 padded atomics/block ----------------
__global__ __launch_bounds__(256) void scatter_kernel(
    const float* __restrict__ x, const int* __restrict__ tok_e,
    const int* __restrict__ base, int* __restrict__ cursor,
    int* __restrict__ invrow, u16* __restrict__ A1)
{
    __shared__ int hist[NE], gbase[NE], rows[64];
    int b  = blockIdx.x;
    int t0 = b * 32;
    if (threadIdx.x < NE) hist[threadIdx.x] = 0;
    __syncthreads();
    if (threadIdx.x == 0) {
        for (int s = 0; s < 64; ++s) {
            int e = tok_e[t0 * 2 + s];
            rows[s] = hist[e]++;
        }
        for (int e = 0; e < NE; ++e)
            gbase[e] = atomicAdd(&cursor[e * 16], hist[e]);
        for (int s = 0; s < 64; ++s) {
            int e = tok_e[t0 * 2 + s];
            int row = base[e] + gbase[e] + rows[s];
            rows[s] = row;
            invrow[t0 * 2 + s] = row;
        }
    }
    __syncthreads();
    int i = threadIdx.x;
    for (int t = 0; t < 32; ++t) {
        float4 xv = ((const float4*)(x + (size_t)(t0 + t) * DIM))[i];
        u32 p0 = pk2(xv.x, xv.y);
        u32 p1 = pk2(xv.z, xv.w);
        int r0 = rows[2 * t], r1 = rows[2 * t + 1];
        u32* d0 = (u32*)(A1 + (size_t)r0 * DIM) + i * 2;
        d0[0] = p0; d0[1] = p1;
        u32* d1 = (u32*)(A1 + (size_t)r1 * DIM) + i * 2;
        d1[0] = p0; d1[1] = p1;
    }
}

// ---------------- fp32 -> bf16 weight conversion ----------------
__global__ __launch_bounds__(256) void convw_kernel(
    const float* __restrict__ W1, const float* __restrict__ W2,
    u16* __restrict__ W1b, u16* __restrict__ W2b)
{
    const size_t n8 = (size_t)NE * HID * DIM / 8;
    size_t stride = (size_t)gridDim.x * blockDim.x;
    for (size_t i = blockIdx.x * (size_t)blockDim.x + threadIdx.x; i < 2 * n8; i += stride) {
        const float* src = (i < n8) ? W1 : W2;
        u16*         dst = (i < n8) ? W1b : W2b;
        size_t j = (i < n8) ? i : i - n8;
        float4 a = ((const float4*)src)[j * 2];
        float4 b = ((const float4*)src)[j * 2 + 1];
        uint4 o;
        o.x = pk2(a.x, a.y); o.y = pk2(a.z, a.w);
        o.z = pk2(b.x, b.y); o.w = pk2(b.z, b.w);
        ((uint4*)dst)[j] = o;
    }
}

// ---------------- persistent grouped GEMM — R7/R14-exact inner loop ----------------
// 256x256 tile, BK=32, 8 waves (2Mx4N), 4-slot LDS ring, stage depth-2 (t+2),
// counted vmcnt(4) per K-tile (drain 0 only at item tail). 4-phase-per-2-tiles
// cadence. LDS chunk XOR-swizzle (0 conflicts). Global dynamic queue.
// G2 writes bf16 partials (absmax headroom verified: 0.0156 unchanged).
template<int KDIM, int NDIM, bool IS_G2>
__global__ __launch_bounds__(512, 2) void moe_gemm(
    const u16* __restrict__ A, const u16* __restrict__ B,
    const float* __restrict__ bias,
    u16* __restrict__ Hout, u16* __restrict__ Y0, u16* __restrict__ Y1,
    const int* __restrict__ cnt, const int* __restrict__ base,
    const int* __restrict__ cum, int* __restrict__ qcur)
{
    constexpr int KLEN = IS_G2 ? (KDIM / 2) : KDIM;   // split-K=2 for GEMM2
    constexpr int NKT  = KLEN / 32;                   // 32 (G1) / 64 (G2), even
    constexpr int NI   = NKT / 2;

    __shared__ u16 lds[4 * 16384];        // 4 ring slots x (A 256x32 + B 256x32)
    __shared__ int sitem;

    int tid  = threadIdx.x;
    int lane = tid & 63;
    int w    = tid >> 6;
    int wr   = w >> 2, wc = w & 3;

    // swizzled fragment-read offsets (u16 units), + slot*16384
    int xc   = (lane >> 1) & 3;
    int aOff = (wr * 128 + (lane & 15)) * 32 + (((lane >> 4) ^ xc) * 8);
    int bOff = 8192 + (wc * 64 + (lane & 15)) * 32 + (((lane >> 4) ^ xc) * 8);

    // staging: LDS dest linear; global source chunk inverse-permuted
    int srow = w * 16 + (lane >> 2);      // 0..127
    int scol = (((lane & 3) ^ ((lane >> 3) & 3)) * 8);
    u16* dA0 = lds + (w * 64 + lane) * 8;
    u16* dA1 = dA0 + 4096;
    u16* dB0 = dA0 + 8192;
    u16* dB1 = dA0 + 12288;

    int total = cum[NE];

    for (;;) {
        __syncthreads();                  // protects sitem & LDS reuse across items
        if (tid == 0) {
            int p = atomicAdd(qcur, 1);
            int it = -1;
            if (p < total) {
                int e = 0;
                while (p >= cum[e + 1]) ++e;
                int r   = p - cum[e];
                int mts = (cnt[e * 16] + 255) >> 8;
                int ks = 0, nt, mt;
                if (IS_G2) { int ksnt = r / mts; mt = r - ksnt * mts; ks = ksnt >> 2; nt = ksnt & 3; }
                else       { nt = r / mts; mt = r - nt * mts; }
                it = (e << 16) | (ks << 12) | (nt << 8) | mt;
            }
            sitem = it;
        }
        __syncthreads();
        int item = sitem;
        if (item < 0) break;

        int e  = item >> 16;
        int ks = (item >> 12) & 15;
        int nt = (item >> 8) & 15;
        int mt = item & 255;
        int ce = cnt[e * 16];
        int m0 = base[e] + mt * 256;
        int n0 = nt * 256;
        int k0 = ks * KLEN;

        const u16* aS0 = A + (size_t)(m0 + srow) * KDIM + k0 + scol;
        const u16* aS1 = aS0 + (size_t)128 * KDIM;
        const u16* bS0 = B + (size_t)e * NDIM * KDIM + (size_t)(n0 + srow) * KDIM + k0 + scol;
        const u16* bS1 = bS0 + (size_t)128 * KDIM;

#define STAGE_AB(kt_) do { int b_ = ((kt_) & 3) * 16384; size_t ko_ = (size_t)(kt_) * 32; \
        GLOAD_LDS16(aS0 + ko_, dA0 + b_); GLOAD_LDS16(aS1 + ko_, dA1 + b_); } while (0)
#define STAGE_BB(kt_) do { int b_ = ((kt_) & 3) * 16384; size_t ko_ = (size_t)(kt_) * 32; \
        GLOAD_LDS16(bS0 + ko_, dB0 + b_); GLOAD_LDS16(bS1 + ko_, dB1 + b_); } while (0)

        f32x4 acc[8][4];
        #pragma unroll
        for (int m = 0; m < 8; ++m)
            #pragma unroll
            for (int n = 0; n < 4; ++n)
                #pragma unroll
                for (int i = 0; i < 4; ++i) acc[m][n][i] = 0.f;

        // prologue: tiles 0,1 (8 loads); tile0 landed at vmcnt(4)
        STAGE_AB(0); STAGE_BB(0); STAGE_AB(1); STAGE_BB(1);
        asm volatile("s_waitcnt vmcnt(4)" ::: "memory");
        __builtin_amdgcn_s_barrier();

        for (int i = 0; i < NI; ++i) {
            int t0  = 2 * i, t1 = 2 * i + 1;
            int bo0 = (t0 & 3) * 16384, bo1 = (t1 & 3) * 16384;
            bool st = (i + 1 < NI);
            bf16x8 am[4], bn[4];

            // ---------- phase 1: tile t0, m 0-3 (+ all bn) ----------
            #pragma unroll
            for (int m = 0; m < 4; ++m) am[m] = *(const bf16x8*)(lds + bo0 + aOff + m * 512);
            #pragma unroll
            for (int n = 0; n < 4; ++n) bn[n] = *(const bf16x8*)(lds + bo0 + bOff + n * 512);
            if (st) STAGE_AB(t0 + 2);
            __builtin_amdgcn_s_barrier();
            asm volatile("s_waitcnt lgkmcnt(0)" ::: "memory");
            __builtin_amdgcn_sched_barrier(0);
            __builtin_amdgcn_s_setprio(1);
            #pragma unroll
            for (int m = 0; m < 4; ++m)
                #pragma unroll
                for (int n = 0; n < 4; ++n)
                    acc[m][n] = __builtin_amdgcn_mfma_f32_16x16x32_bf16(am[m], bn[n], acc[m][n], 0, 0, 0);
            __builtin_amdgcn_s_setprio(0);
            __builtin_amdgcn_sched_barrier(0);
            __builtin_amdgcn_s_barrier();

            // ---------- phase 2: tile t0, m 4-7 ----------
            #pragma unroll
            for (int m = 0; m < 4; ++m) am[m] = *(const bf16x8*)(lds + bo0 + aOff + (m + 4) * 512);
            if (st) STAGE_BB(t0 + 2);
            __builtin_amdgcn_s_barrier();
            asm volatile("s_waitcnt lgkmcnt(0)" ::: "memory");
            __builtin_amdgcn_sched_barrier(0);
            __builtin_amdgcn_s_setprio(1);
            #pragma unroll
            for (int m = 0; m < 4; ++m)
                #pragma unroll
                for (int n = 0; n < 4; ++n)
                    acc[m + 4][n] = __builtin_amdgcn_mfma_f32_16x16x32_bf16(am[m], bn[n], acc[m + 4][n], 0, 0, 0);
            __builtin_amdgcn_s_setprio(0);
            __builtin_amdgcn_sched_barrier(0);
            if (st) asm volatile("s_waitcnt vmcnt(4)" ::: "memory");   // tile t1 landed
            else    asm volatile("s_waitcnt vmcnt(0)" ::: "memory");
            __builtin_amdgcn_s_barrier();

            // ---------- phase 3: tile t1, m 0-3 (+ all bn) ----------
            #pragma unroll
            for (int m = 0; m < 4; ++m) am[m] = *(const bf16x8*)(lds + bo1 + aOff + m * 512);
            #pragma unroll
            for (int n = 0; n < 4; ++n) bn[n] = *(const bf16x8*)(lds + bo1 + bOff + n * 512);
            if (st) STAGE_AB(t1 + 2);
            __builtin_amdgcn_s_barrier();
            asm volatile("s_waitcnt lgkmcnt(0)" ::: "memory");
            __builtin_amdgcn_sched_barrier(0);
            __builtin_amdgcn_s_setprio(1);
            #pragma unroll
            for (int m = 0; m < 4; ++m)
                #pragma unroll
                for (int n = 0; n < 4; ++n)
                    acc[m][n] = __builtin_amdgcn_mfma_f32_16x16x32_bf16(am[m], bn[n], acc[m][n], 0, 0, 0);
            __builtin_amdgcn_s_setprio(0);
            __builtin_amdgcn_sched_barrier(0);
            __builtin_amdgcn_s_barrier();

            // ---------- phase 4: tile t1, m 4-7 ----------
            #pragma unroll
            for (int m = 0; m < 4; ++m) am[m] = *(const bf16x8*)(lds + bo1 + aOff + (m + 4) * 512);
            if (st) STAGE_BB(t1 + 2);
            __builtin_amdgcn_s_barrier();
            asm volatile("s_waitcnt lgkmcnt(0)" ::: "memory");
            __builtin_amdgcn_sched_barrier(0);
            __builtin_amdgcn_s_setprio(1);
            #pragma unroll
            for (int m = 0; m < 4; ++m)
                #pragma unroll
                for (int n = 0; n < 4; ++n)
                    acc[m + 4][n] = __builtin_amdgcn_mfma_f32_16x16x32_bf16(am[m], bn[n], acc[m + 4][n], 0, 0, 0);
            __builtin_amdgcn_s_setprio(0);
            __builtin_amdgcn_sched_barrier(0);
            if (st) asm volatile("s_waitcnt vmcnt(4)" ::: "memory");   // tile t0+2 landed
            __builtin_amdgcn_s_barrier();
        }
#undef STAGE_AB
#undef STAGE_BB

        // epilogue: C/D layout col = lane&15, row = (lane>>4)*4 + reg
        #pragma unroll
        for (int m = 0; m < 8; ++m) {
            #pragma unroll
            for (int j = 0; j < 4; ++j) {
                int rr   = wr * 128 + m * 16 + (lane >> 4) * 4 + j;
                int rloc = mt * 256 + rr;
                if (rloc < ce) {
                    if (!IS_G2) {
                        u16* hp = Hout + (size_t)(m0 + rr) * NDIM;
                        #pragma unroll
                        for (int n = 0; n < 4; ++n) {
                            int gcol = n0 + wc * 64 + n * 16 + (lane & 15);
                            float v = acc[m][n][j] + bias[e * NDIM + gcol];
                            v = v > 0.f ? v : 0.f;
                            hp[gcol] = f2bf(v);
                        }
                    } else {
                        u16* yp = (ks == 0 ? Y0 : Y1) + (size_t)(m0 + rr) * NDIM;
                        #pragma unroll
                        for (int n = 0; n < 4; ++n) {
                            int gcol = n0 + wc * 64 + n * 16 + (lane & 15);
                            float v = acc[m][n][j];
                            if (ks == 0) v += bias[e * NDIM + gcol];
                            yp[gcol] = f2bf(v);
                        }
                    }
                }
            }
        }
        asm volatile("s_waitcnt vmcnt(0)" ::: "memory");   // drain stores: ledger sound
    }
}

// ---------------- combine (bf16 partials): out = w0*(Y0[r0]+Y1[r0]) + w1*(Y0[r1]+Y1[r1]) ----------------
__global__ __launch_bounds__(256) void combine_kernel(
    const u16* __restrict__ Y0, const u16* __restrict__ Y1,
    const int* __restrict__ invrow, const float* __restrict__ tok_w,
    float* __restrict__ out)
{
    int t  = blockIdx.x;
    int r0 = invrow[t * 2], r1 = invrow[t * 2 + 1];
    float w0 = tok_w[t * 2], w1 = tok_w[t * 2 + 1];
    int i = threadIdx.x;
    ushort4 a0 = ((const ushort4*)(Y0 + (size_t)r0 * DIM))[i];
    ushort4 b0 = ((const ushort4*)(Y1 + (size_t)r0 * DIM))[i];
    ushort4 a1 = ((const ushort4*)(Y0 + (size_t)r1 * DIM))[i];
    ushort4 b1 = ((const ushort4*)(Y1 + (size_t)r1 * DIM))[i];
    float4 o;
    o.x = w0 * (bf2f(a0.x) + bf2f(b0.x)) + w1 * (bf2f(a1.x) + bf2f(b1.x));
    o.y = w0 * (bf2f(a0.y) + bf2f(b0.y)) + w1 * (bf2f(a1.y) + bf2f(b1.y));
    o.z = w0 * (bf2f(a0.z) + bf2f(b0.z)) + w1 * (bf2f(a1.z) + bf2f(b1.z));
    o.w = w0 * (bf2f(a0.w) + bf2f(b0.w)) + w1 * (bf2f(a1.w) + bf2f(b1.w));
    ((float4*)(out + (size_t)t * DIM))[i] = o;
}

extern "C" void kernel_launch(void* const* d_in, const int* in_sizes, int n_in,
                              void* d_out, int out_size, void* d_ws, size_t ws_size,
                              hipStream_t stream) {
    const float* xs = (const float*)d_in[0];
    const float* gw = (const float*)d_in[1];
    const float* W1 = (const float*)d_in[2];
    const float* b1 = (const float*)d_in[3];
    const float* W2 = (const float*)d_in[4];
    const float* b2 = (const float*)d_in[5];
    float* out = (float*)d_out;

    char* ws = (char*)d_ws;
    size_t off = 0;
    auto alloc = [&](size_t bytes) -> void* {
        off = (off + 255) & ~(size_t)255;
        void* p = ws + off;
        off += bytes;
        return p;
    };
    int*   ctrs   = (int*)alloc(2048);          // cnt[e*16] @0, cursor[e*16] @+128 ints
    int*   cnt    = ctrs;
    int*   cursor = ctrs + 128;
    int*   base   = (int*)alloc(64);
    int*   qmeta  = (int*)alloc(256);           // cum1[9], cum2[9]@16, qcur@32,33
    int*   tok_e  = (int*)alloc((size_t)T_TOK * 2 * 4);
    float* tok_w  = (float*)alloc((size_t)T_TOK * 2 * 4);
    int*   invrow = (int*)alloc((size_t)T_TOK * 2 * 4);
    u16*   A1     = (u16*)alloc((size_t)RCAP * DIM * 2);       // 34 MB
    u16*   W1b    = (u16*)alloc((size_t)NE * HID * DIM * 2);   // 64 MB
    u16*   W2b    = (u16*)alloc((size_t)NE * HID * DIM * 2);   // 64 MB
    u16*   hbuf   = (u16*)alloc((size_t)RCAP * HID * 2);       // 136 MB
    u16*   Ypart0 = (u16*)alloc((size_t)RCAP * DIM * 2);       // 34 MB bf16
    u16*   Ypart1 = (u16*)alloc((size_t)RCAP * DIM * 2);       // 34 MB bf16
    (void)ws_size; (void)in_sizes; (void)n_in; (void)out_size;

    hipMemsetAsync(ctrs, 0, 2048, stream);

    router_kernel<<<T_TOK / 4, 256, 0, stream>>>(xs, gw, tok_e, tok_w, cnt);
    prefix_kernel<<<1, 64, 0, stream>>>(cnt, base, qmeta);
    scatter_kernel<<<T_TOK / 32, 256, 0, stream>>>(xs, tok_e, base, cursor, invrow, A1);
    convw_kernel<<<2048, 256, 0, stream>>>(W1, W2, W1b, W2b);

    moe_gemm<DIM, HID, false><<<256, 512, 0, stream>>>(
        A1, W1b, b1, hbuf, nullptr, nullptr, cnt, base, qmeta, qmeta + 32);
    moe_gemm<HID, DIM, true><<<256, 512, 0, stream>>>(
        hbuf, W2b, b2, nullptr, Ypart0, Ypart1, cnt, base, qmeta + 16, qmeta + 33);

    combine_kernel<<<T_TOK, 256, 0, stream>>>(Ypart0, Ypart1, invrow, tok_w, out);
}